// Round 2
// baseline (104.117 us; speedup 1.0000x reference)
//
#include <hip/hip_runtime.h>

#define M_ROWS 8192   // B*L
#define DIM    768    // D
#define HCH    128    // H

typedef __bf16 bf16x8 __attribute__((ext_vector_type(8)));
typedef float  f32x4  __attribute__((ext_vector_type(4)));

__device__ __forceinline__ unsigned short f2bf(float f) {
    union { float f; unsigned int u; } v; v.f = f;
    unsigned int u = v.u;
    u += 0x7fffu + ((u >> 16) & 1u);   // round-to-nearest-even
    return (unsigned short)(u >> 16);
}
__device__ __forceinline__ unsigned int pk2bf(float x, float y) {
    return (unsigned int)f2bf(x) | ((unsigned int)f2bf(y) << 16);
}

// Fused: convert W0 f32->bf16 during staging + GEMM (M=8192,N=128,K=768 bf16
// MFMA) + relu + weighted H-reduction into s1/s2.
// Block: 256 thr = 4 waves; each wave owns a 32-col strip of all 16 rows.
// Grid: 512 (16 rows/block) -> 2 blocks/CU, 8 waves/CU.
__global__ __launch_bounds__(256) void gemm_s_kernel(
    const float* __restrict__ text,
    const float* __restrict__ W0,
    const float* __restrict__ b0,
    const float* __restrict__ W1,
    float* __restrict__ s1, float* __restrict__ s2)
{
    // row stride 40 bf16 = 80 B: frag b128 reads alias only 2-way (free)
    __shared__ unsigned short As[16][40];
    __shared__ unsigned short Bs[128][40];
    __shared__ float red1[16][4];
    __shared__ float red2[16][4];

    const int tid  = threadIdx.x;
    const int lane = tid & 63;
    const int wave = tid >> 6;
    const int row0 = blockIdx.x * 16;

    const int n16  = lane & 15;
    const int quad = lane >> 4;
    const int wcol = wave * 32;          // this wave's 32-col strip

    // staging maps
    const int ar = tid >> 3;             // A (t<128): 16 rows x 32 k, 1 float4
    const int ak = (tid & 7) << 2;
    const int br = tid >> 1;             // B: 128 rows x 32 k, 4 float4/thread
    const int bk = (tid & 1) << 4;

    const float* aptr = text + (size_t)(row0 + ar) * DIM + ak;
    const float* bptr = W0 + (size_t)br * DIM + bk;

    f32x4 acc[2];
    acc[0] = (f32x4){0.f, 0.f, 0.f, 0.f};
    acc[1] = (f32x4){0.f, 0.f, 0.f, 0.f};

    float4 av, bv[4];
    if (tid < 128) av = *(const float4*)aptr;
    #pragma unroll
    for (int q = 0; q < 4; ++q) bv[q] = *(const float4*)(bptr + q * 4);

    for (int kt = 0; kt < DIM; kt += 32) {
        const int ktn = (kt + 32 < DIM) ? (kt + 32) : 0;   // harmless reload on last iter
        float4 av_n, bv_n[4];
        if (tid < 128) av_n = *(const float4*)(aptr + ktn);
        #pragma unroll
        for (int q = 0; q < 4; ++q) bv_n[q] = *(const float4*)(bptr + ktn + q * 4);

        // stage current tile into LDS (f32 -> bf16 on the fly)
        if (tid < 128) {
            uint2 o;
            o.x = pk2bf(av.x, av.y);
            o.y = pk2bf(av.z, av.w);
            *(uint2*)&As[ar][ak] = o;
        }
        uint4 ob;
        ob.x = pk2bf(bv[0].x, bv[0].y);
        ob.y = pk2bf(bv[0].z, bv[0].w);
        ob.z = pk2bf(bv[1].x, bv[1].y);
        ob.w = pk2bf(bv[1].z, bv[1].w);
        *(uint4*)&Bs[br][bk] = ob;
        ob.x = pk2bf(bv[2].x, bv[2].y);
        ob.y = pk2bf(bv[2].z, bv[2].w);
        ob.z = pk2bf(bv[3].x, bv[3].y);
        ob.w = pk2bf(bv[3].z, bv[3].w);
        *(uint4*)&Bs[br][bk + 8] = ob;
        __syncthreads();

        bf16x8 a   = *(const bf16x8*)&As[n16][quad * 8];
        bf16x8 bf0 = *(const bf16x8*)&Bs[wcol +  0 + n16][quad * 8];
        bf16x8 bf1 = *(const bf16x8*)&Bs[wcol + 16 + n16][quad * 8];
        acc[0] = __builtin_amdgcn_mfma_f32_16x16x32_bf16(a, bf0, acc[0], 0, 0, 0);
        acc[1] = __builtin_amdgcn_mfma_f32_16x16x32_bf16(a, bf1, acc[1], 0, 0, 0);
        __syncthreads();

        av = av_n;
        #pragma unroll
        for (int q = 0; q < 4; ++q) bv[q] = bv_n[q];
    }

    // epilogue: relu + b0, weight by w_a / w_b, reduce this wave's 32 cols.
    // C/D layout (verified): col = lane&15 (+tile), row = quad*4 + reg
    float p1[4] = {0.f, 0.f, 0.f, 0.f};
    float p2[4] = {0.f, 0.f, 0.f, 0.f};
    #pragma unroll
    for (int j = 0; j < 2; ++j) {
        const int col = wcol + j * 16 + n16;
        const float bb = b0[col];
        const float wa = W1[col];
        const float wb = W1[HCH + col];
        #pragma unroll
        for (int r = 0; r < 4; ++r) {
            float h = acc[j][r] + bb;
            h = fmaxf(h, 0.f);
            p1[r] += h * wa;
            p2[r] += h * wb;
        }
    }
    // reduce across the 16 lanes of each quad (masks < 16 stay inside the quad)
    #pragma unroll
    for (int r = 0; r < 4; ++r) {
        #pragma unroll
        for (int m = 8; m >= 1; m >>= 1) {
            p1[r] += __shfl_xor(p1[r], m);
            p2[r] += __shfl_xor(p2[r], m);
        }
    }
    if (n16 == 0) {
        #pragma unroll
        for (int r = 0; r < 4; ++r) {
            const int rr = quad * 4 + r;      // row within the 16
            red1[rr][wave] = p1[r];
            red2[rr][wave] = p2[r];
        }
    }
    __syncthreads();
    if (tid < 16) {
        s1[row0 + tid] = red1[tid][0] + red1[tid][1] + red1[tid][2] + red1[tid][3];
        s2[row0 + tid] = red2[tid][0] + red2[tid][1] + red2[tid][2] + red2[tid][3];
    }
}

// out[b][i][j] = sigmoid(s1[b*1024+i] + s2[b*1024+j] + b1)
// grid = 8192 (one block per (b,i) row), 256 thr x float4 = 1024 j's
__global__ __launch_bounds__(256) void outer_sigmoid_kernel(
    const float* __restrict__ s1, const float* __restrict__ s2,
    const float* __restrict__ b1, float* __restrict__ out)
{
    const int bi = blockIdx.x;
    const int b  = bi >> 10;
    const float base = s1[bi] + b1[0];
    const float4 t = ((const float4*)(s2 + (b << 10)))[threadIdx.x];
    float4 r;
    r.x = 1.f / (1.f + __expf(-(base + t.x)));
    r.y = 1.f / (1.f + __expf(-(base + t.y)));
    r.z = 1.f / (1.f + __expf(-(base + t.z)));
    r.w = 1.f / (1.f + __expf(-(base + t.w)));
    ((float4*)out)[((size_t)bi << 8) + threadIdx.x] = r;
}

extern "C" void kernel_launch(void* const* d_in, const int* in_sizes, int n_in,
                              void* d_out, int out_size, void* d_ws, size_t ws_size,
                              hipStream_t stream)
{
    const float* text = (const float*)d_in[0];
    // d_in[1] = mask: all-ones, unused by the reference math
    const float* W0 = (const float*)d_in[2];
    const float* b0 = (const float*)d_in[3];
    const float* W1 = (const float*)d_in[4];
    const float* b1 = (const float*)d_in[5];
    float* out = (float*)d_out;

    // workspace layout: [s1: 32 KB][s2: 32 KB]
    float* s1 = (float*)d_ws;
    float* s2 = s1 + M_ROWS;

    gemm_s_kernel<<<512, 256, 0, stream>>>(text, W0, b0, W1, s1, s2);
    outer_sigmoid_kernel<<<8192, 256, 0, stream>>>(s1, s2, b1, out);
}